// Round 1
// baseline (527.606 us; speedup 1.0000x reference)
//
#include <hip/hip_runtime.h>
#include <stdint.h>

#define NEXP 16
#define KSEL 4
#define HDIM 2048
#define IDIM 1024
#define TTOK 2048

typedef __attribute__((ext_vector_type(8))) short bf16x8;
typedef __attribute__((ext_vector_type(4))) float f32x4;

__device__ __forceinline__ uint32_t f2bf_u(float x) {
  uint32_t u = __builtin_bit_cast(uint32_t, x);
  return (u + 0x7fffu + ((u >> 16) & 1u)) >> 16;  // RNE bf16
}
__device__ __forceinline__ uint32_t pack2(float a, float b) {
  return f2bf_u(a) | (f2bf_u(b) << 16);
}

// ---------------- router: logits, top-4, softmax, x->bf16 ----------------
__global__ __launch_bounds__(256) void router_kernel(
    const float* __restrict__ x, const float* __restrict__ gw,
    ushort* __restrict__ xb, int* __restrict__ topk_id,
    float* __restrict__ topk_w, int* __restrict__ counts)
{
  const int wid = threadIdx.x >> 6;
  const int lane = threadIdx.x & 63;
  const int t = blockIdx.x * 4 + wid;
  const float4* x4 = (const float4*)(x + (size_t)t * HDIM);
  const float4* gw4 = (const float4*)gw;
  float acc[NEXP];
#pragma unroll
  for (int e = 0; e < NEXP; ++e) acc[e] = 0.f;
#pragma unroll
  for (int i = 0; i < HDIM / 256; ++i) {  // 8 iters of float4
    const int idx = i * 64 + lane;
    float4 xv = x4[idx];
    uint2 xp;
    xp.x = pack2(xv.x, xv.y);
    xp.y = pack2(xv.z, xv.w);
    *(uint2*)(xb + (size_t)t * HDIM + idx * 4) = xp;
#pragma unroll
    for (int e = 0; e < NEXP; ++e) {
      float4 wv = gw4[e * (HDIM / 4) + idx];
      acc[e] += xv.x * wv.x + xv.y * wv.y + xv.z * wv.z + xv.w * wv.w;
    }
  }
#pragma unroll
  for (int e = 0; e < NEXP; ++e) {
#pragma unroll
    for (int off = 32; off >= 1; off >>= 1)
      acc[e] += __shfl_xor(acc[e], off);
  }
  if (lane == 0) {
    unsigned taken = 0;
    float vals[KSEL];
    int ids[KSEL];
#pragma unroll
    for (int k = 0; k < KSEL; ++k) {
      float bv = -3.4e38f; int bi = 0;
      for (int e = 0; e < NEXP; ++e)
        if (!((taken >> e) & 1u) && acc[e] > bv) { bv = acc[e]; bi = e; }
      taken |= 1u << bi; vals[k] = bv; ids[k] = bi;
    }
    float m = vals[0], s = 0.f, w[KSEL];
#pragma unroll
    for (int k = 0; k < KSEL; ++k) { w[k] = __expf(vals[k] - m); s += w[k]; }
    float is = 1.f / s;
#pragma unroll
    for (int k = 0; k < KSEL; ++k) {
      topk_id[t * KSEL + k] = ids[k];
      topk_w[t * KSEL + k] = w[k] * is;
      atomicAdd(&counts[ids[k]], 1);
    }
  }
}

// ---------------- offsets: exclusive prefix over 16 counts ----------------
__global__ void offsets_kernel(const int* __restrict__ counts, int* __restrict__ offsets) {
  if (threadIdx.x == 0) {
    int s = 0;
    for (int e = 0; e < NEXP; ++e) { offsets[e] = s; s += counts[e]; }
    offsets[NEXP] = s;
  }
}

// ---------------- scatter: bucket tokens by expert ----------------
__global__ __launch_bounds__(256) void scatter_kernel(
    const int* __restrict__ topk_id, const int* __restrict__ offsets,
    int* __restrict__ cursors, int* __restrict__ rowTok, int* __restrict__ inv)
{
  const int t = blockIdx.x * 256 + threadIdx.x;
  if (t >= TTOK) return;
#pragma unroll
  for (int k = 0; k < KSEL; ++k) {
    const int e = topk_id[t * KSEL + k];
    const int pos = atomicAdd(&cursors[e], 1);
    const int row = offsets[e] + pos;
    rowTok[row] = t;
    inv[t * KSEL + k] = row;
  }
}

// ---------------- GEMM1: h = silu(x.w1g^T) * (x.w1u^T), sparse rows -------
__global__ __launch_bounds__(256, 2) void gemm1_kernel(
    const ushort* __restrict__ xb, const float* __restrict__ w1g,
    const float* __restrict__ w1u, const int* __restrict__ rowTok,
    const int* __restrict__ counts, const int* __restrict__ offsets,
    ushort* __restrict__ hbuf)
{
  const int e = blockIdx.z;
  const int n_e = counts[e];
  const int mt = blockIdx.y;
  if (mt * 128 >= n_e) return;
  const int nt = blockIdx.x;
  const int rowbase = offsets[e];

  __shared__ ushort As[2][128 * 32];
  __shared__ ushort Bg[2][128 * 32];
  __shared__ ushort Bu[2][128 * 32];

  const int tid = threadIdx.x;
  const int sr = tid >> 1;            // staged row 0..127
  const int sc = (tid & 1) << 4;      // col base 0 or 16

  const int arow = mt * 128 + sr;
  const int tokA = rowTok[rowbase + (arow < n_e ? arow : (n_e - 1))];
  const ushort* aSrc = xb + (size_t)tokA * HDIM + sc;
  const float* bgSrc = w1g + (size_t)e * IDIM * HDIM + (size_t)(nt * 128 + sr) * HDIM + sc;
  const float* buSrc = w1u + (size_t)e * IDIM * HDIM + (size_t)(nt * 128 + sr) * HDIM + sc;

  uint4 aR0, aR1;
  float4 g0, g1, g2, g3, u0, u1, u2, u3;

  auto LOAD = [&](int kt) {
    const int k0 = kt * 32;
    aR0 = *(const uint4*)(aSrc + k0);
    aR1 = *(const uint4*)(aSrc + k0 + 8);
    g0 = *(const float4*)(bgSrc + k0);
    g1 = *(const float4*)(bgSrc + k0 + 4);
    g2 = *(const float4*)(bgSrc + k0 + 8);
    g3 = *(const float4*)(bgSrc + k0 + 12);
    u0 = *(const float4*)(buSrc + k0);
    u1 = *(const float4*)(buSrc + k0 + 4);
    u2 = *(const float4*)(buSrc + k0 + 8);
    u3 = *(const float4*)(buSrc + k0 + 12);
  };
  auto STORE = [&](int b) {
    *(uint4*)&As[b][sr * 32 + sc] = aR0;
    *(uint4*)&As[b][sr * 32 + sc + 8] = aR1;
    uint4 t0;
    t0.x = pack2(g0.x, g0.y); t0.y = pack2(g0.z, g0.w);
    t0.z = pack2(g1.x, g1.y); t0.w = pack2(g1.z, g1.w);
    *(uint4*)&Bg[b][sr * 32 + sc] = t0;
    t0.x = pack2(g2.x, g2.y); t0.y = pack2(g2.z, g2.w);
    t0.z = pack2(g3.x, g3.y); t0.w = pack2(g3.z, g3.w);
    *(uint4*)&Bg[b][sr * 32 + sc + 8] = t0;
    t0.x = pack2(u0.x, u0.y); t0.y = pack2(u0.z, u0.w);
    t0.z = pack2(u1.x, u1.y); t0.w = pack2(u1.z, u1.w);
    *(uint4*)&Bu[b][sr * 32 + sc] = t0;
    t0.x = pack2(u2.x, u2.y); t0.y = pack2(u2.z, u2.w);
    t0.z = pack2(u3.x, u3.y); t0.w = pack2(u3.z, u3.w);
    *(uint4*)&Bu[b][sr * 32 + sc + 8] = t0;
  };

  const int lane = tid & 63;
  const int wid = tid >> 6;
  const int wr = (wid >> 1) << 6;   // wave row offset 0/64
  const int wc = (wid & 1) << 6;    // wave col offset 0/64
  const int lr = lane & 15;
  const int lk = (lane >> 4) << 3;

  f32x4 accG[4][4], accU[4][4];
#pragma unroll
  for (int i = 0; i < 4; ++i)
#pragma unroll
    for (int j = 0; j < 4; ++j) {
      accG[i][j] = (f32x4){0.f, 0.f, 0.f, 0.f};
      accU[i][j] = (f32x4){0.f, 0.f, 0.f, 0.f};
    }

  const int NT = HDIM / 32;  // 64
  LOAD(0);
  STORE(0);
  LOAD(1);
  __syncthreads();

  for (int kt = 0; kt < NT; ++kt) {
    const int cur = kt & 1;
    if (kt + 1 < NT) STORE(cur ^ 1);
    if (kt + 2 < NT) LOAD(kt + 2);

    bf16x8 af[4], bgf[4], buf_[4];
#pragma unroll
    for (int mi = 0; mi < 4; ++mi)
      af[mi] = *(const bf16x8*)&As[cur][(wr + mi * 16 + lr) * 32 + lk];
#pragma unroll
    for (int ni = 0; ni < 4; ++ni) {
      bgf[ni] = *(const bf16x8*)&Bg[cur][(wc + ni * 16 + lr) * 32 + lk];
      buf_[ni] = *(const bf16x8*)&Bu[cur][(wc + ni * 16 + lr) * 32 + lk];
    }
#pragma unroll
    for (int mi = 0; mi < 4; ++mi)
#pragma unroll
      for (int ni = 0; ni < 4; ++ni) {
        accG[mi][ni] = __builtin_amdgcn_mfma_f32_16x16x32_bf16(af[mi], bgf[ni], accG[mi][ni], 0, 0, 0);
        accU[mi][ni] = __builtin_amdgcn_mfma_f32_16x16x32_bf16(af[mi], buf_[ni], accU[mi][ni], 0, 0, 0);
      }
    __syncthreads();
  }

#pragma unroll
  for (int mi = 0; mi < 4; ++mi) {
#pragma unroll
    for (int ni = 0; ni < 4; ++ni) {
      const int col = nt * 128 + wc + ni * 16 + lr;
#pragma unroll
      for (int r = 0; r < 4; ++r) {
        const int mrow = mt * 128 + wr + mi * 16 + ((lane >> 4) << 2) + r;
        if (mrow < n_e) {
          const float gv = accG[mi][ni][r];
          const float uv = accU[mi][ni][r];
          const float hv = (gv / (1.f + __expf(-gv))) * uv;
          hbuf[(size_t)(rowbase + mrow) * IDIM + col] = (ushort)f2bf_u(hv);
        }
      }
    }
  }
}

// ---------------- GEMM2: po = h . w2^T (per expert), fp32 out -------------
__global__ __launch_bounds__(256, 2) void gemm2_kernel(
    const ushort* __restrict__ hbuf, const float* __restrict__ w2,
    const int* __restrict__ counts, const int* __restrict__ offsets,
    float* __restrict__ po)
{
  const int e = blockIdx.z;
  const int n_e = counts[e];
  const int mt = blockIdx.y;
  if (mt * 128 >= n_e) return;
  const int nt = blockIdx.x;
  const int rowbase = offsets[e];

  __shared__ ushort As[2][128 * 32];
  __shared__ ushort Bs[2][128 * 32];

  const int tid = threadIdx.x;
  const int sr = tid >> 1;
  const int sc = (tid & 1) << 4;

  const int arow = mt * 128 + sr;
  const int grow = rowbase + (arow < n_e ? arow : (n_e - 1));
  const ushort* aSrc = hbuf + (size_t)grow * IDIM + sc;
  const float* bSrc = w2 + (size_t)e * HDIM * IDIM + (size_t)(nt * 128 + sr) * IDIM + sc;

  uint4 aR0, aR1;
  float4 b0, b1, b2, b3;

  auto LOAD = [&](int kt) {
    const int k0 = kt * 32;
    aR0 = *(const uint4*)(aSrc + k0);
    aR1 = *(const uint4*)(aSrc + k0 + 8);
    b0 = *(const float4*)(bSrc + k0);
    b1 = *(const float4*)(bSrc + k0 + 4);
    b2 = *(const float4*)(bSrc + k0 + 8);
    b3 = *(const float4*)(bSrc + k0 + 12);
  };
  auto STORE = [&](int b) {
    *(uint4*)&As[b][sr * 32 + sc] = aR0;
    *(uint4*)&As[b][sr * 32 + sc + 8] = aR1;
    uint4 t0;
    t0.x = pack2(b0.x, b0.y); t0.y = pack2(b0.z, b0.w);
    t0.z = pack2(b1.x, b1.y); t0.w = pack2(b1.z, b1.w);
    *(uint4*)&Bs[b][sr * 32 + sc] = t0;
    t0.x = pack2(b2.x, b2.y); t0.y = pack2(b2.z, b2.w);
    t0.z = pack2(b3.x, b3.y); t0.w = pack2(b3.z, b3.w);
    *(uint4*)&Bs[b][sr * 32 + sc + 8] = t0;
  };

  const int lane = tid & 63;
  const int wid = tid >> 6;
  const int wr = (wid >> 1) << 6;
  const int wc = (wid & 1) << 6;
  const int lr = lane & 15;
  const int lk = (lane >> 4) << 3;

  f32x4 acc[4][4];
#pragma unroll
  for (int i = 0; i < 4; ++i)
#pragma unroll
    for (int j = 0; j < 4; ++j) acc[i][j] = (f32x4){0.f, 0.f, 0.f, 0.f};

  const int NT = IDIM / 32;  // 32
  LOAD(0);
  STORE(0);
  LOAD(1);
  __syncthreads();

  for (int kt = 0; kt < NT; ++kt) {
    const int cur = kt & 1;
    if (kt + 1 < NT) STORE(cur ^ 1);
    if (kt + 2 < NT) LOAD(kt + 2);

    bf16x8 af[4], bf[4];
#pragma unroll
    for (int mi = 0; mi < 4; ++mi)
      af[mi] = *(const bf16x8*)&As[cur][(wr + mi * 16 + lr) * 32 + lk];
#pragma unroll
    for (int ni = 0; ni < 4; ++ni)
      bf[ni] = *(const bf16x8*)&Bs[cur][(wc + ni * 16 + lr) * 32 + lk];
#pragma unroll
    for (int mi = 0; mi < 4; ++mi)
#pragma unroll
      for (int ni = 0; ni < 4; ++ni)
        acc[mi][ni] = __builtin_amdgcn_mfma_f32_16x16x32_bf16(af[mi], bf[ni], acc[mi][ni], 0, 0, 0);
    __syncthreads();
  }

#pragma unroll
  for (int mi = 0; mi < 4; ++mi) {
#pragma unroll
    for (int ni = 0; ni < 4; ++ni) {
      const int col = nt * 128 + wc + ni * 16 + lr;
#pragma unroll
      for (int r = 0; r < 4; ++r) {
        const int mrow = mt * 128 + wr + mi * 16 + ((lane >> 4) << 2) + r;
        if (mrow < n_e)
          po[(size_t)(rowbase + mrow) * HDIM + col] = acc[mi][ni][r];
      }
    }
  }
}

// ---------------- combine: out[t] = sum_k w_k * po[row_k] -----------------
__global__ __launch_bounds__(256) void combine_kernel(
    const float* __restrict__ po, const int* __restrict__ inv,
    const float* __restrict__ tw, float* __restrict__ out)
{
  const int t = blockIdx.x;
  const int r0 = inv[t * 4 + 0], r1 = inv[t * 4 + 1];
  const int r2 = inv[t * 4 + 2], r3 = inv[t * 4 + 3];
  const float w0 = tw[t * 4 + 0], w1 = tw[t * 4 + 1];
  const float w2v = tw[t * 4 + 2], w3 = tw[t * 4 + 3];
  const float4* p0 = (const float4*)(po + (size_t)r0 * HDIM);
  const float4* p1 = (const float4*)(po + (size_t)r1 * HDIM);
  const float4* p2 = (const float4*)(po + (size_t)r2 * HDIM);
  const float4* p3 = (const float4*)(po + (size_t)r3 * HDIM);
  float4* o4 = (float4*)(out + (size_t)t * HDIM);
  for (int i = threadIdx.x; i < HDIM / 4; i += 256) {
    float4 a = p0[i], b = p1[i], c = p2[i], d = p3[i];
    float4 o;
    o.x = w0 * a.x + w1 * b.x + w2v * c.x + w3 * d.x;
    o.y = w0 * a.y + w1 * b.y + w2v * c.y + w3 * d.y;
    o.z = w0 * a.z + w1 * b.z + w2v * c.z + w3 * d.z;
    o.w = w0 * a.w + w1 * b.w + w2v * c.w + w3 * d.w;
    o4[i] = o;
  }
}

extern "C" void kernel_launch(void* const* d_in, const int* in_sizes, int n_in,
                              void* d_out, int out_size, void* d_ws, size_t ws_size,
                              hipStream_t stream) {
  const float* x   = (const float*)d_in[0];
  const float* gw  = (const float*)d_in[1];
  const float* w1g = (const float*)d_in[2];
  const float* w1u = (const float*)d_in[3];
  const float* w2  = (const float*)d_in[4];
  float* out = (float*)d_out;

  char* ws = (char*)d_ws;
  // layout (bytes, 256-aligned):
  //   xb     [TTOK*HDIM] bf16            @ 0          (8 MiB)
  //   hbuf   [TTOK*KSEL, IDIM] bf16      @ 8388608    (16 MiB)
  //   po     [TTOK*KSEL, HDIM] fp32      @ 25165824   (64 MiB)
  //   topk_id[TTOK*4] int                @ 92274688
  //   topk_w [TTOK*4] f32                @ 92307456
  //   rowTok [TTOK*4] int                @ 92340224
  //   inv    [TTOK*4] int                @ 92372992
  //   ctrl   counts[16] cursors[16] offsets[17] @ 92405760
  ushort* xb     = (ushort*)(ws + 0);
  ushort* hbuf   = (ushort*)(ws + 8388608);
  float*  po     = (float*) (ws + 25165824);
  int*    tkid   = (int*)   (ws + 92274688);
  float*  tkw    = (float*) (ws + 92307456);
  int*    rowTok = (int*)   (ws + 92340224);
  int*    inv    = (int*)   (ws + 92372992);
  int*    ctrl   = (int*)   (ws + 92405760);
  int* counts  = ctrl;
  int* cursors = ctrl + 16;
  int* offsets = ctrl + 32;

  hipMemsetAsync(ctrl, 0, 256, stream);
  router_kernel<<<TTOK / 4, 256, 0, stream>>>(x, gw, xb, tkid, tkw, counts);
  offsets_kernel<<<1, 64, 0, stream>>>(counts, offsets);
  scatter_kernel<<<TTOK / 256, 256, 0, stream>>>(tkid, offsets, cursors, rowTok, inv);
  dim3 g1(IDIM / 128, TTOK / 128, NEXP);
  gemm1_kernel<<<g1, 256, 0, stream>>>(xb, w1g, w1u, rowTok, counts, offsets, hbuf);
  dim3 g2(HDIM / 128, TTOK / 128, NEXP);
  gemm2_kernel<<<g2, 256, 0, stream>>>(hbuf, w2, counts, offsets, po);
  combine_kernel<<<TTOK, 256, 0, stream>>>(po, inv, tkw, out);
}

// Round 3
// 484.046 us; speedup vs baseline: 1.0900x; 1.0900x over previous
//
#include <hip/hip_runtime.h>
#include <hip/hip_bf16.h>
#include <stdint.h>

#define NEXP 16
#define KSEL 4
#define HDIM 2048
#define IDIM 1024
#define TTOK 2048
#define MAXTILES 80

typedef __attribute__((ext_vector_type(8))) short bf16x8;
typedef __attribute__((ext_vector_type(4))) float f32x4;

__device__ __forceinline__ uint32_t pack2(float a, float b) {
  __hip_bfloat162 h = __float22bfloat162_rn(float2{a, b});
  uint32_t u;
  __builtin_memcpy(&u, &h, 4);
  return u;
}
__device__ __forceinline__ ushort bf1(float a) {
  __hip_bfloat16 h = __float2bfloat16(a);
  ushort u;
  __builtin_memcpy(&u, &h, 2);
  return u;
}
// LDS tiles are [128 rows][32 bf16] (64B rows). XOR-swizzle the 16B-chunk
// position with row bits so ds_read_b128 frag reads (16 rows, same chunk)
// spread over 8 bank-quads (2-way = free, m136) instead of 8/16-way.
__device__ __forceinline__ int swz32(int row, int ecol) {
  return row * 32 + (ecol ^ (((row >> 1) & 3) << 3));
}

// ---------------- router: logits, top-4, softmax, x->bf16 ----------------
__global__ __launch_bounds__(256) void router_kernel(
    const float* __restrict__ x, const float* __restrict__ gw,
    ushort* __restrict__ xb, int* __restrict__ topk_id,
    float* __restrict__ topk_w, int* __restrict__ counts)
{
  const int wid = threadIdx.x >> 6;
  const int lane = threadIdx.x & 63;
  const int t = blockIdx.x * 4 + wid;
  const float4* x4 = (const float4*)(x + (size_t)t * HDIM);
  const float4* gw4 = (const float4*)gw;
  float acc[NEXP];
#pragma unroll
  for (int e = 0; e < NEXP; ++e) acc[e] = 0.f;
#pragma unroll
  for (int i = 0; i < HDIM / 256; ++i) {
    const int idx = i * 64 + lane;
    float4 xv = x4[idx];
    uint2 xp;
    xp.x = pack2(xv.x, xv.y);
    xp.y = pack2(xv.z, xv.w);
    *(uint2*)(xb + (size_t)t * HDIM + idx * 4) = xp;
#pragma unroll
    for (int e = 0; e < NEXP; ++e) {
      float4 wv = gw4[e * (HDIM / 4) + idx];
      acc[e] += xv.x * wv.x + xv.y * wv.y + xv.z * wv.z + xv.w * wv.w;
    }
  }
#pragma unroll
  for (int e = 0; e < NEXP; ++e) {
#pragma unroll
    for (int off = 32; off >= 1; off >>= 1)
      acc[e] += __shfl_xor(acc[e], off);
  }
  if (lane == 0) {
    unsigned taken = 0;
    float vals[KSEL];
    int ids[KSEL];
#pragma unroll
    for (int k = 0; k < KSEL; ++k) {
      float bv = -3.4e38f; int bi = 0;
      for (int e = 0; e < NEXP; ++e)
        if (!((taken >> e) & 1u) && acc[e] > bv) { bv = acc[e]; bi = e; }
      taken |= 1u << bi; vals[k] = bv; ids[k] = bi;
    }
    float m = vals[0], s = 0.f, w[KSEL];
#pragma unroll
    for (int k = 0; k < KSEL; ++k) { w[k] = __expf(vals[k] - m); s += w[k]; }
    float is = 1.f / s;
#pragma unroll
    for (int k = 0; k < KSEL; ++k) {
      topk_id[t * KSEL + k] = ids[k];
      topk_w[t * KSEL + k] = w[k] * is;
      atomicAdd(&counts[ids[k]], 1);
    }
  }
}

// ------------- offsets + tile map (all-active GEMM grid) -----------------
__global__ void offsets_kernel(const int* __restrict__ counts, int* __restrict__ offsets,
                               int* __restrict__ nTiles, int* __restrict__ tileE,
                               int* __restrict__ tileM) {
  if (threadIdx.x == 0) {
    int s = 0, nt = 0;
    for (int e = 0; e < NEXP; ++e) {
      offsets[e] = s;
      const int tiles = (counts[e] + 127) >> 7;
      for (int m = 0; m < tiles; ++m) { tileE[nt] = e; tileM[nt] = m; ++nt; }
      s += counts[e];
    }
    offsets[NEXP] = s;
    *nTiles = nt;
  }
}

// ---------------- scatter: bucket tokens by expert ----------------
__global__ __launch_bounds__(256) void scatter_kernel(
    const int* __restrict__ topk_id, const int* __restrict__ offsets,
    int* __restrict__ cursors, int* __restrict__ rowTok, int* __restrict__ inv)
{
  const int t = blockIdx.x * 256 + threadIdx.x;
  if (t >= TTOK) return;
#pragma unroll
  for (int k = 0; k < KSEL; ++k) {
    const int e = topk_id[t * KSEL + k];
    const int pos = atomicAdd(&cursors[e], 1);
    const int row = offsets[e] + pos;
    rowTok[row] = t;
    inv[t * KSEL + k] = row;
  }
}

// ---------------- GEMM1: h = silu(x.w1g^T) * (x.w1u^T), sparse rows -------
__global__ __launch_bounds__(256, 2) void gemm1_kernel(
    const ushort* __restrict__ xb, const float* __restrict__ w1g,
    const float* __restrict__ w1u, const int* __restrict__ rowTok,
    const int* __restrict__ counts, const int* __restrict__ offsets,
    const int* __restrict__ nTiles, const int* __restrict__ tileE,
    const int* __restrict__ tileM, ushort* __restrict__ hbuf)
{
  const int ti = blockIdx.y;
  if (ti >= *nTiles) return;
  const int e = tileE[ti];
  const int mt = tileM[ti];
  const int n_e = counts[e];
  const int nt = blockIdx.x;
  const int rowbase = offsets[e];

  __shared__ ushort As[2][128 * 32];
  __shared__ ushort Bg[2][128 * 32];
  __shared__ ushort Bu[2][128 * 32];

  const int tid = threadIdx.x;
  const int sr = tid >> 1;            // staged row 0..127
  const int sc = (tid & 1) << 4;      // col base 0 or 16

  const int arow = mt * 128 + sr;
  const int tokA = rowTok[rowbase + (arow < n_e ? arow : (n_e - 1))];
  const ushort* aSrc = xb + (size_t)tokA * HDIM + sc;
  const float* bgSrc = w1g + (size_t)e * IDIM * HDIM + (size_t)(nt * 128 + sr) * HDIM + sc;
  const float* buSrc = w1u + (size_t)e * IDIM * HDIM + (size_t)(nt * 128 + sr) * HDIM + sc;

  uint4 aR0, aR1;
  float4 g0, g1, g2, g3, u0, u1, u2, u3;

  auto LOAD = [&](int kt) {
    const int k0 = kt * 32;
    aR0 = *(const uint4*)(aSrc + k0);
    aR1 = *(const uint4*)(aSrc + k0 + 8);
    g0 = *(const float4*)(bgSrc + k0);
    g1 = *(const float4*)(bgSrc + k0 + 4);
    g2 = *(const float4*)(bgSrc + k0 + 8);
    g3 = *(const float4*)(bgSrc + k0 + 12);
    u0 = *(const float4*)(buSrc + k0);
    u1 = *(const float4*)(buSrc + k0 + 4);
    u2 = *(const float4*)(buSrc + k0 + 8);
    u3 = *(const float4*)(buSrc + k0 + 12);
  };
  auto STORE = [&](int b) {
    *(uint4*)&As[b][swz32(sr, sc)] = aR0;
    *(uint4*)&As[b][swz32(sr, sc + 8)] = aR1;
    uint4 t0;
    t0.x = pack2(g0.x, g0.y); t0.y = pack2(g0.z, g0.w);
    t0.z = pack2(g1.x, g1.y); t0.w = pack2(g1.z, g1.w);
    *(uint4*)&Bg[b][swz32(sr, sc)] = t0;
    t0.x = pack2(g2.x, g2.y); t0.y = pack2(g2.z, g2.w);
    t0.z = pack2(g3.x, g3.y); t0.w = pack2(g3.z, g3.w);
    *(uint4*)&Bg[b][swz32(sr, sc + 8)] = t0;
    t0.x = pack2(u0.x, u0.y); t0.y = pack2(u0.z, u0.w);
    t0.z = pack2(u1.x, u1.y); t0.w = pack2(u1.z, u1.w);
    *(uint4*)&Bu[b][swz32(sr, sc)] = t0;
    t0.x = pack2(u2.x, u2.y); t0.y = pack2(u2.z, u2.w);
    t0.z = pack2(u3.x, u3.y); t0.w = pack2(u3.z, u3.w);
    *(uint4*)&Bu[b][swz32(sr, sc + 8)] = t0;
  };

  const int lane = tid & 63;
  const int wid = tid >> 6;
  const int wr = (wid >> 1) << 6;   // wave row offset 0/64
  const int wc = (wid & 1) << 6;    // wave col offset 0/64
  const int lr = lane & 15;
  const int lk = (lane >> 4) << 3;

  f32x4 accG[4][4], accU[4][4];
#pragma unroll
  for (int i = 0; i < 4; ++i)
#pragma unroll
    for (int j = 0; j < 4; ++j) {
      accG[i][j] = (f32x4){0.f, 0.f, 0.f, 0.f};
      accU[i][j] = (f32x4){0.f, 0.f, 0.f, 0.f};
    }

  const int NT = HDIM / 32;  // 64
  LOAD(0);
  STORE(0);
  LOAD(1);
  __syncthreads();

  for (int kt = 0; kt < NT; ++kt) {
    const int cur = kt & 1;

    bf16x8 af[4], bgf[4], buf_[4];
#pragma unroll
    for (int mi = 0; mi < 4; ++mi)
      af[mi] = *(const bf16x8*)&As[cur][swz32(wr + mi * 16 + lr, lk)];
#pragma unroll
    for (int ni = 0; ni < 4; ++ni) {
      bgf[ni] = *(const bf16x8*)&Bg[cur][swz32(wc + ni * 16 + lr, lk)];
      buf_[ni] = *(const bf16x8*)&Bu[cur][swz32(wc + ni * 16 + lr, lk)];
    }

    if (kt + 1 < NT) STORE(cur ^ 1);
    if (kt + 2 < NT) LOAD(kt + 2);

#pragma unroll
    for (int mi = 0; mi < 4; ++mi)
#pragma unroll
      for (int ni = 0; ni < 4; ++ni) {
        accG[mi][ni] = __builtin_amdgcn_mfma_f32_16x16x32_bf16(af[mi], bgf[ni], accG[mi][ni], 0, 0, 0);
        accU[mi][ni] = __builtin_amdgcn_mfma_f32_16x16x32_bf16(af[mi], buf_[ni], accU[mi][ni], 0, 0, 0);
      }
    __syncthreads();
  }

#pragma unroll
  for (int mi = 0; mi < 4; ++mi) {
#pragma unroll
    for (int ni = 0; ni < 4; ++ni) {
      const int col = nt * 128 + wc + ni * 16 + lr;
#pragma unroll
      for (int r = 0; r < 4; ++r) {
        const int mrow = mt * 128 + wr + mi * 16 + ((lane >> 4) << 2) + r;
        if (mrow < n_e) {
          const float gv = accG[mi][ni][r];
          const float uv = accU[mi][ni][r];
          const float hv = (gv / (1.f + __expf(-gv))) * uv;
          hbuf[(size_t)(rowbase + mrow) * IDIM + col] = bf1(hv);
        }
      }
    }
  }
}

// ---------------- GEMM2: po = h . w2^T (per expert), bf16 out -------------
__global__ __launch_bounds__(256, 2) void gemm2_kernel(
    const ushort* __restrict__ hbuf, const float* __restrict__ w2,
    const int* __restrict__ counts, const int* __restrict__ offsets,
    const int* __restrict__ nTiles, const int* __restrict__ tileE,
    const int* __restrict__ tileM, ushort* __restrict__ po)
{
  const int ti = blockIdx.y;
  if (ti >= *nTiles) return;
  const int e = tileE[ti];
  const int mt = tileM[ti];
  const int n_e = counts[e];
  const int nt = blockIdx.x;
  const int rowbase = offsets[e];

  __shared__ ushort As[2][128 * 32];
  __shared__ ushort Bs[2][128 * 32];

  const int tid = threadIdx.x;
  const int sr = tid >> 1;
  const int sc = (tid & 1) << 4;

  const int arow = mt * 128 + sr;
  const int grow = rowbase + (arow < n_e ? arow : (n_e - 1));
  const ushort* aSrc = hbuf + (size_t)grow * IDIM + sc;
  const float* bSrc = w2 + (size_t)e * HDIM * IDIM + (size_t)(nt * 128 + sr) * IDIM + sc;

  uint4 aR0, aR1;
  float4 b0, b1, b2, b3;

  auto LOAD = [&](int kt) {
    const int k0 = kt * 32;
    aR0 = *(const uint4*)(aSrc + k0);
    aR1 = *(const uint4*)(aSrc + k0 + 8);
    b0 = *(const float4*)(bSrc + k0);
    b1 = *(const float4*)(bSrc + k0 + 4);
    b2 = *(const float4*)(bSrc + k0 + 8);
    b3 = *(const float4*)(bSrc + k0 + 12);
  };
  auto STORE = [&](int b) {
    *(uint4*)&As[b][swz32(sr, sc)] = aR0;
    *(uint4*)&As[b][swz32(sr, sc + 8)] = aR1;
    uint4 t0;
    t0.x = pack2(b0.x, b0.y); t0.y = pack2(b0.z, b0.w);
    t0.z = pack2(b1.x, b1.y); t0.w = pack2(b1.z, b1.w);
    *(uint4*)&Bs[b][swz32(sr, sc)] = t0;
    t0.x = pack2(b2.x, b2.y); t0.y = pack2(b2.z, b2.w);
    t0.z = pack2(b3.x, b3.y); t0.w = pack2(b3.z, b3.w);
    *(uint4*)&Bs[b][swz32(sr, sc + 8)] = t0;
  };

  const int lane = tid & 63;
  const int wid = tid >> 6;
  const int wr = (wid >> 1) << 6;
  const int wc = (wid & 1) << 6;
  const int lr = lane & 15;
  const int lk = (lane >> 4) << 3;

  f32x4 acc[4][4];
#pragma unroll
  for (int i = 0; i < 4; ++i)
#pragma unroll
    for (int j = 0; j < 4; ++j) acc[i][j] = (f32x4){0.f, 0.f, 0.f, 0.f};

  const int NT = IDIM / 32;  // 32
  LOAD(0);
  STORE(0);
  LOAD(1);
  __syncthreads();

  for (int kt = 0; kt < NT; ++kt) {
    const int cur = kt & 1;

    bf16x8 af[4], bf[4];
#pragma unroll
    for (int mi = 0; mi < 4; ++mi)
      af[mi] = *(const bf16x8*)&As[cur][swz32(wr + mi * 16 + lr, lk)];
#pragma unroll
    for (int ni = 0; ni < 4; ++ni)
      bf[ni] = *(const bf16x8*)&Bs[cur][swz32(wc + ni * 16 + lr, lk)];

    if (kt + 1 < NT) STORE(cur ^ 1);
    if (kt + 2 < NT) LOAD(kt + 2);

#pragma unroll
    for (int mi = 0; mi < 4; ++mi)
#pragma unroll
      for (int ni = 0; ni < 4; ++ni)
        acc[mi][ni] = __builtin_amdgcn_mfma_f32_16x16x32_bf16(af[mi], bf[ni], acc[mi][ni], 0, 0, 0);
    __syncthreads();
  }

#pragma unroll
  for (int mi = 0; mi < 4; ++mi) {
#pragma unroll
    for (int ni = 0; ni < 4; ++ni) {
      const int col = nt * 128 + wc + ni * 16 + lr;
#pragma unroll
      for (int r = 0; r < 4; ++r) {
        const int mrow = mt * 128 + wr + mi * 16 + ((lane >> 4) << 2) + r;
        if (mrow < n_e)
          po[(size_t)(rowbase + mrow) * HDIM + col] = bf1(acc[mi][ni][r]);
      }
    }
  }
}

// ---------------- combine: out[t] = sum_k w_k * po[row_k] -----------------
__global__ __launch_bounds__(256) void combine_kernel(
    const ushort* __restrict__ po, const int* __restrict__ inv,
    const float* __restrict__ tw, float* __restrict__ out)
{
  const int t = blockIdx.x;
  const int r0 = inv[t * 4 + 0], r1 = inv[t * 4 + 1];
  const int r2 = inv[t * 4 + 2], r3 = inv[t * 4 + 3];
  const float w0 = tw[t * 4 + 0], w1 = tw[t * 4 + 1];
  const float w2v = tw[t * 4 + 2], w3 = tw[t * 4 + 3];
  const int i = threadIdx.x;  // HDIM/8 == 256 lanes, 8 elems each
  uint4 v0 = *(const uint4*)(po + (size_t)r0 * HDIM + i * 8);
  uint4 v1 = *(const uint4*)(po + (size_t)r1 * HDIM + i * 8);
  uint4 v2 = *(const uint4*)(po + (size_t)r2 * HDIM + i * 8);
  uint4 v3 = *(const uint4*)(po + (size_t)r3 * HDIM + i * 8);
  float o[8];
#pragma unroll
  for (int w = 0; w < 4; ++w) {
    const uint32_t a = (&v0.x)[w], b = (&v1.x)[w], c = (&v2.x)[w], d = (&v3.x)[w];
    o[w * 2 + 0] = w0 * __builtin_bit_cast(float, a << 16) +
                   w1 * __builtin_bit_cast(float, b << 16) +
                   w2v * __builtin_bit_cast(float, c << 16) +
                   w3 * __builtin_bit_cast(float, d << 16);
    o[w * 2 + 1] = w0 * __builtin_bit_cast(float, a & 0xffff0000u) +
                   w1 * __builtin_bit_cast(float, b & 0xffff0000u) +
                   w2v * __builtin_bit_cast(float, c & 0xffff0000u) +
                   w3 * __builtin_bit_cast(float, d & 0xffff0000u);
  }
  float4* o4 = (float4*)(out + (size_t)t * HDIM + i * 8);
  o4[0] = (float4){o[0], o[1], o[2], o[3]};
  o4[1] = (float4){o[4], o[5], o[6], o[7]};
}

extern "C" void kernel_launch(void* const* d_in, const int* in_sizes, int n_in,
                              void* d_out, int out_size, void* d_ws, size_t ws_size,
                              hipStream_t stream) {
  const float* x   = (const float*)d_in[0];
  const float* gw  = (const float*)d_in[1];
  const float* w1g = (const float*)d_in[2];
  const float* w1u = (const float*)d_in[3];
  const float* w2  = (const float*)d_in[4];
  float* out = (float*)d_out;

  char* ws = (char*)d_ws;
  // layout (bytes):
  //   xb     [TTOK*HDIM] bf16       @ 0           (8 MiB)
  //   hbuf   [8192,1024] bf16       @ 8388608     (16 MiB)
  //   po     [8192,2048] bf16       @ 25165824    (32 MiB)
  //   tkid   [TTOK*4] int           @ 58720256
  //   tkw    [TTOK*4] f32           @ 58753024
  //   rowTok [TTOK*4] int           @ 58785792
  //   inv    [TTOK*4] int           @ 58818560
  //   ctrl                          @ 58851328    (1 KiB)
  ushort* xb     = (ushort*)(ws + 0);
  ushort* hbuf   = (ushort*)(ws + 8388608);
  ushort* po     = (ushort*)(ws + 25165824);
  int*    tkid   = (int*)   (ws + 58720256);
  float*  tkw    = (float*) (ws + 58753024);
  int*    rowTok = (int*)   (ws + 58785792);
  int*    inv    = (int*)   (ws + 58818560);
  int*    ctrl   = (int*)   (ws + 58851328);
  int* counts  = ctrl;         // 16
  int* cursors = ctrl + 16;    // 16
  int* offsets = ctrl + 32;    // 17
  int* nTiles  = ctrl + 49;    // 1
  int* tileE   = ctrl + 50;    // 80
  int* tileM   = ctrl + 130;   // 80

  (void)hipMemsetAsync(ctrl, 0, 1024, stream);
  router_kernel<<<TTOK / 4, 256, 0, stream>>>(x, gw, xb, tkid, tkw, counts);
  offsets_kernel<<<1, 64, 0, stream>>>(counts, offsets, nTiles, tileE, tileM);
  scatter_kernel<<<TTOK / 256, 256, 0, stream>>>(tkid, offsets, cursors, rowTok, inv);
  dim3 g1(IDIM / 128, MAXTILES);
  gemm1_kernel<<<g1, 256, 0, stream>>>(xb, w1g, w1u, rowTok, counts, offsets,
                                       nTiles, tileE, tileM, hbuf);
  dim3 g2(HDIM / 128, MAXTILES);
  gemm2_kernel<<<g2, 256, 0, stream>>>(hbuf, w2, counts, offsets,
                                       nTiles, tileE, tileM, po);
  combine_kernel<<<TTOK, 256, 0, stream>>>(po, inv, tkw, out);
}

// Round 4
// 468.864 us; speedup vs baseline: 1.1253x; 1.0324x over previous
//
#include <hip/hip_runtime.h>
#include <hip/hip_bf16.h>
#include <stdint.h>

#define NEXP 16
#define KSEL 4
#define HDIM 2048
#define IDIM 1024
#define TTOK 2048
#define MAXTILES 80
#define NT1 16            // gemm1 n-tiles (IDIM/64)
#define NT2 32            // gemm2 n-tiles (HDIM/64)
#define MAXB1 (MAXTILES * NT1)   // 1280, divisible by 8
#define MAXB2 (MAXTILES * NT2)   // 2560, divisible by 8

typedef __attribute__((ext_vector_type(8))) short bf16x8;
typedef __attribute__((ext_vector_type(4))) float f32x4;

__device__ __forceinline__ uint32_t pack2(float a, float b) {
  __hip_bfloat162 h = __float22bfloat162_rn(float2{a, b});
  uint32_t u;
  __builtin_memcpy(&u, &h, 4);
  return u;
}
__device__ __forceinline__ ushort bf1(float a) {
  __hip_bfloat16 h = __float2bfloat16(a);
  ushort u;
  __builtin_memcpy(&u, &h, 2);
  return u;
}
// LDS tiles are [rows][32 bf16] (64B rows). XOR-swizzle the 16B-chunk
// position with row bits: frag reads (16 rows, same chunk) and staged writes
// both land 2-way per bank group (free, m136). Verified 0 conflicts in R3.
__device__ __forceinline__ int swz32(int row, int ecol) {
  return row * 32 + (ecol ^ (((row >> 1) & 3) << 3));
}

// ---------------- router: logits, top-4, softmax, x->bf16 ----------------
__global__ __launch_bounds__(256) void router_kernel(
    const float* __restrict__ x, const float* __restrict__ gw,
    ushort* __restrict__ xb, int* __restrict__ topk_id,
    float* __restrict__ topk_w, int* __restrict__ counts)
{
  const int wid = threadIdx.x >> 6;
  const int lane = threadIdx.x & 63;
  const int t = blockIdx.x * 4 + wid;
  const float4* x4 = (const float4*)(x + (size_t)t * HDIM);
  const float4* gw4 = (const float4*)gw;
  float acc[NEXP];
#pragma unroll
  for (int e = 0; e < NEXP; ++e) acc[e] = 0.f;
#pragma unroll
  for (int i = 0; i < HDIM / 256; ++i) {
    const int idx = i * 64 + lane;
    float4 xv = x4[idx];
    uint2 xp;
    xp.x = pack2(xv.x, xv.y);
    xp.y = pack2(xv.z, xv.w);
    *(uint2*)(xb + (size_t)t * HDIM + idx * 4) = xp;
#pragma unroll
    for (int e = 0; e < NEXP; ++e) {
      float4 wv = gw4[e * (HDIM / 4) + idx];
      acc[e] += xv.x * wv.x + xv.y * wv.y + xv.z * wv.z + xv.w * wv.w;
    }
  }
#pragma unroll
  for (int e = 0; e < NEXP; ++e) {
#pragma unroll
    for (int off = 32; off >= 1; off >>= 1)
      acc[e] += __shfl_xor(acc[e], off);
  }
  if (lane == 0) {
    unsigned taken = 0;
    float vals[KSEL];
    int ids[KSEL];
#pragma unroll
    for (int k = 0; k < KSEL; ++k) {
      float bv = -3.4e38f; int bi = 0;
      for (int e = 0; e < NEXP; ++e)
        if (!((taken >> e) & 1u) && acc[e] > bv) { bv = acc[e]; bi = e; }
      taken |= 1u << bi; vals[k] = bv; ids[k] = bi;
    }
    float m = vals[0], s = 0.f, w[KSEL];
#pragma unroll
    for (int k = 0; k < KSEL; ++k) { w[k] = __expf(vals[k] - m); s += w[k]; }
    float is = 1.f / s;
#pragma unroll
    for (int k = 0; k < KSEL; ++k) {
      topk_id[t * KSEL + k] = ids[k];
      topk_w[t * KSEL + k] = w[k] * is;
      atomicAdd(&counts[ids[k]], 1);
    }
  }
}

// ------ plan: offsets + 1D work lists, (e, nt-major, mt-inner) order ------
__global__ void plan_kernel(const int* __restrict__ counts, int* __restrict__ offsets,
                            int* __restrict__ nW1, int* __restrict__ nW2,
                            int* __restrict__ wl1, int* __restrict__ wl2) {
  __shared__ int tiles[NEXP], pre[NEXP];
  const int tid = threadIdx.x;
  if (tid == 0) {
    int s = 0, p = 0;
    for (int e = 0; e < NEXP; ++e) {
      offsets[e] = s; s += counts[e];
      tiles[e] = (counts[e] + 127) >> 7;
      pre[e] = p; p += tiles[e];
    }
    offsets[NEXP] = s;
    *nW1 = p * NT1;
    *nW2 = p * NT2;
  }
  __syncthreads();
  if (tid < NEXP) {
    const int e = tid, T = tiles[e];
    int idx = pre[e] * NT1;
    for (int nt = 0; nt < NT1; ++nt)
      for (int mt = 0; mt < T; ++mt)
        wl1[idx++] = (e << 12) | (nt << 6) | mt;
  } else if (tid < 2 * NEXP) {
    const int e = tid - NEXP, T = tiles[e];
    int idx = pre[e] * NT2;
    for (int nt = 0; nt < NT2; ++nt)
      for (int mt = 0; mt < T; ++mt)
        wl2[idx++] = (e << 12) | (nt << 6) | mt;
  }
}

// ---------------- scatter: bucket tokens by expert ----------------
__global__ __launch_bounds__(256) void scatter_kernel(
    const int* __restrict__ topk_id, const int* __restrict__ offsets,
    int* __restrict__ cursors, int* __restrict__ rowTok, int* __restrict__ inv)
{
  const int t = blockIdx.x * 256 + threadIdx.x;
  if (t >= TTOK) return;
#pragma unroll
  for (int k = 0; k < KSEL; ++k) {
    const int e = topk_id[t * KSEL + k];
    const int pos = atomicAdd(&cursors[e], 1);
    const int row = offsets[e] + pos;
    rowTok[row] = t;
    inv[t * KSEL + k] = row;
  }
}

// -------- GEMM1: h = silu(x.w1g^T) * (x.w1u^T). BM=128 BN=64 BK=32 --------
__global__ __launch_bounds__(256, 3) void gemm1_kernel(
    const ushort* __restrict__ xb, const float* __restrict__ w1g,
    const float* __restrict__ w1u, const int* __restrict__ rowTok,
    const int* __restrict__ counts, const int* __restrict__ offsets,
    const int* __restrict__ nW1, const int* __restrict__ wl1,
    ushort* __restrict__ hbuf)
{
  const int nTot = *nW1;
  // XCD-chunked bijection: consecutive logical L (mt-siblings sharing a
  // weight panel) land on the same XCD -> panel re-reads hit that XCD's L2.
  const int L = (blockIdx.x & 7) * (MAXB1 / 8) + (blockIdx.x >> 3);
  if (L >= nTot) return;
  const int w = wl1[L];
  const int e = w >> 12, nt = (w >> 6) & 63, mt = w & 63;
  const int n_e = counts[e], rowbase = offsets[e];

  __shared__ ushort As[2][128 * 32];
  __shared__ ushort Bg[2][64 * 32];
  __shared__ ushort Bu[2][64 * 32];

  const int tid = threadIdx.x;
  const int sr = tid >> 2;           // row 0..63
  const int sc = (tid & 3) << 3;     // elem col base 0/8/16/24
  const int r0 = mt * 128 + sr;
  const int r1 = r0 + 64;
  const int tok0 = rowTok[rowbase + (r0 < n_e ? r0 : n_e - 1)];
  const int tok1 = rowTok[rowbase + (r1 < n_e ? r1 : n_e - 1)];
  const ushort* aS0 = xb + (size_t)tok0 * HDIM + sc;
  const ushort* aS1 = xb + (size_t)tok1 * HDIM + sc;
  const float* gS = w1g + (size_t)e * IDIM * HDIM + (size_t)(nt * 64 + sr) * HDIM + sc;
  const float* uS = w1u + (size_t)e * IDIM * HDIM + (size_t)(nt * 64 + sr) * HDIM + sc;

  uint4 aR0, aR1;
  float4 gL, gH, uL, uH;

  auto LOAD = [&](int kt) {
    const int k0 = kt * 32;
    aR0 = *(const uint4*)(aS0 + k0);
    aR1 = *(const uint4*)(aS1 + k0);
    gL = *(const float4*)(gS + k0);
    gH = *(const float4*)(gS + k0 + 4);
    uL = *(const float4*)(uS + k0);
    uH = *(const float4*)(uS + k0 + 4);
  };
  auto STORE = [&](int b) {
    *(uint4*)&As[b][swz32(sr, sc)] = aR0;
    *(uint4*)&As[b][swz32(sr + 64, sc)] = aR1;
    uint4 t0;
    t0.x = pack2(gL.x, gL.y); t0.y = pack2(gL.z, gL.w);
    t0.z = pack2(gH.x, gH.y); t0.w = pack2(gH.z, gH.w);
    *(uint4*)&Bg[b][swz32(sr, sc)] = t0;
    t0.x = pack2(uL.x, uL.y); t0.y = pack2(uL.z, uL.w);
    t0.z = pack2(uH.x, uH.y); t0.w = pack2(uH.z, uH.w);
    *(uint4*)&Bu[b][swz32(sr, sc)] = t0;
  };

  const int lane = tid & 63;
  const int wid = tid >> 6;
  const int wr = (wid >> 1) << 6;   // wave row 0/64
  const int wc = (wid & 1) << 5;    // wave col 0/32
  const int lr = lane & 15;
  const int lk = (lane >> 4) << 3;

  f32x4 accG[4][2], accU[4][2];
#pragma unroll
  for (int i = 0; i < 4; ++i)
#pragma unroll
    for (int j = 0; j < 2; ++j) {
      accG[i][j] = (f32x4){0.f, 0.f, 0.f, 0.f};
      accU[i][j] = (f32x4){0.f, 0.f, 0.f, 0.f};
    }

  const int NT = HDIM / 32;  // 64
  LOAD(0);
  STORE(0);
  LOAD(1);
  __syncthreads();

  for (int kt = 0; kt < NT; ++kt) {
    const int cur = kt & 1;

    bf16x8 af[4], bgf[2], buf_[2];
#pragma unroll
    for (int mi = 0; mi < 4; ++mi)
      af[mi] = *(const bf16x8*)&As[cur][swz32(wr + mi * 16 + lr, lk)];
#pragma unroll
    for (int ni = 0; ni < 2; ++ni) {
      bgf[ni] = *(const bf16x8*)&Bg[cur][swz32(wc + ni * 16 + lr, lk)];
      buf_[ni] = *(const bf16x8*)&Bu[cur][swz32(wc + ni * 16 + lr, lk)];
    }

    if (kt + 1 < NT) STORE(cur ^ 1);
    if (kt + 2 < NT) LOAD(kt + 2);

#pragma unroll
    for (int mi = 0; mi < 4; ++mi)
#pragma unroll
      for (int ni = 0; ni < 2; ++ni) {
        accG[mi][ni] = __builtin_amdgcn_mfma_f32_16x16x32_bf16(af[mi], bgf[ni], accG[mi][ni], 0, 0, 0);
        accU[mi][ni] = __builtin_amdgcn_mfma_f32_16x16x32_bf16(af[mi], buf_[ni], accU[mi][ni], 0, 0, 0);
      }
    __syncthreads();
  }

#pragma unroll
  for (int mi = 0; mi < 4; ++mi) {
#pragma unroll
    for (int ni = 0; ni < 2; ++ni) {
      const int col = nt * 64 + wc + ni * 16 + lr;
#pragma unroll
      for (int r = 0; r < 4; ++r) {
        const int mrow = mt * 128 + wr + mi * 16 + ((lane >> 4) << 2) + r;
        if (mrow < n_e) {
          const float gv = accG[mi][ni][r];
          const float uv = accU[mi][ni][r];
          const float hv = (gv / (1.f + __expf(-gv))) * uv;
          hbuf[(size_t)(rowbase + mrow) * IDIM + col] = bf1(hv);
        }
      }
    }
  }
}

// -------- GEMM2: po = h . w2^T (per expert). BM=128 BN=64 BK=32 -----------
__global__ __launch_bounds__(256, 4) void gemm2_kernel(
    const ushort* __restrict__ hbuf, const float* __restrict__ w2,
    const int* __restrict__ counts, const int* __restrict__ offsets,
    const int* __restrict__ nW2, const int* __restrict__ wl2,
    ushort* __restrict__ po)
{
  const int nTot = *nW2;
  const int L = (blockIdx.x & 7) * (MAXB2 / 8) + (blockIdx.x >> 3);
  if (L >= nTot) return;
  const int w = wl2[L];
  const int e = w >> 12, nt = (w >> 6) & 63, mt = w & 63;
  const int n_e = counts[e], rowbase = offsets[e];

  __shared__ ushort As[2][128 * 32];
  __shared__ ushort Bs[2][64 * 32];

  const int tid = threadIdx.x;
  const int sr = tid >> 2;
  const int sc = (tid & 3) << 3;
  const int r0 = mt * 128 + sr;
  const int r1 = r0 + 64;
  const int g0 = rowbase + (r0 < n_e ? r0 : n_e - 1);
  const int g1 = rowbase + (r1 < n_e ? r1 : n_e - 1);
  const ushort* aS0 = hbuf + (size_t)g0 * IDIM + sc;
  const ushort* aS1 = hbuf + (size_t)g1 * IDIM + sc;
  const float* bS = w2 + (size_t)e * HDIM * IDIM + (size_t)(nt * 64 + sr) * IDIM + sc;

  uint4 aR0, aR1;
  float4 bL, bH;

  auto LOAD = [&](int kt) {
    const int k0 = kt * 32;
    aR0 = *(const uint4*)(aS0 + k0);
    aR1 = *(const uint4*)(aS1 + k0);
    bL = *(const float4*)(bS + k0);
    bH = *(const float4*)(bS + k0 + 4);
  };
  auto STORE = [&](int b) {
    *(uint4*)&As[b][swz32(sr, sc)] = aR0;
    *(uint4*)&As[b][swz32(sr + 64, sc)] = aR1;
    uint4 t0;
    t0.x = pack2(bL.x, bL.y); t0.y = pack2(bL.z, bL.w);
    t0.z = pack2(bH.x, bH.y); t0.w = pack2(bH.z, bH.w);
    *(uint4*)&Bs[b][swz32(sr, sc)] = t0;
  };

  const int lane = tid & 63;
  const int wid = tid >> 6;
  const int wr = (wid >> 1) << 6;
  const int wc = (wid & 1) << 5;
  const int lr = lane & 15;
  const int lk = (lane >> 4) << 3;

  f32x4 acc[4][2];
#pragma unroll
  for (int i = 0; i < 4; ++i)
#pragma unroll
    for (int j = 0; j < 2; ++j) acc[i][j] = (f32x4){0.f, 0.f, 0.f, 0.f};

  const int NT = IDIM / 32;  // 32
  LOAD(0);
  STORE(0);
  LOAD(1);
  __syncthreads();

  for (int kt = 0; kt < NT; ++kt) {
    const int cur = kt & 1;

    bf16x8 af[4], bf[2];
#pragma unroll
    for (int mi = 0; mi < 4; ++mi)
      af[mi] = *(const bf16x8*)&As[cur][swz32(wr + mi * 16 + lr, lk)];
#pragma unroll
    for (int ni = 0; ni < 2; ++ni)
      bf[ni] = *(const bf16x8*)&Bs[cur][swz32(wc + ni * 16 + lr, lk)];

    if (kt + 1 < NT) STORE(cur ^ 1);
    if (kt + 2 < NT) LOAD(kt + 2);

#pragma unroll
    for (int mi = 0; mi < 4; ++mi)
#pragma unroll
      for (int ni = 0; ni < 2; ++ni)
        acc[mi][ni] = __builtin_amdgcn_mfma_f32_16x16x32_bf16(af[mi], bf[ni], acc[mi][ni], 0, 0, 0);
    __syncthreads();
  }

#pragma unroll
  for (int mi = 0; mi < 4; ++mi) {
#pragma unroll
    for (int ni = 0; ni < 2; ++ni) {
      const int col = nt * 64 + wc + ni * 16 + lr;
#pragma unroll
      for (int r = 0; r < 4; ++r) {
        const int mrow = mt * 128 + wr + mi * 16 + ((lane >> 4) << 2) + r;
        if (mrow < n_e)
          po[(size_t)(rowbase + mrow) * HDIM + col] = bf1(acc[mi][ni][r]);
      }
    }
  }
}

// ---------------- combine: out[t] = sum_k w_k * po[row_k] -----------------
__global__ __launch_bounds__(256) void combine_kernel(
    const ushort* __restrict__ po, const int* __restrict__ inv,
    const float* __restrict__ tw, float* __restrict__ out)
{
  const int t = blockIdx.x;
  const int r0 = inv[t * 4 + 0], r1 = inv[t * 4 + 1];
  const int r2 = inv[t * 4 + 2], r3 = inv[t * 4 + 3];
  const float w0 = tw[t * 4 + 0], w1 = tw[t * 4 + 1];
  const float w2v = tw[t * 4 + 2], w3 = tw[t * 4 + 3];
  const int i = threadIdx.x;  // HDIM/8 == 256 lanes, 8 elems each
  uint4 v0 = *(const uint4*)(po + (size_t)r0 * HDIM + i * 8);
  uint4 v1 = *(const uint4*)(po + (size_t)r1 * HDIM + i * 8);
  uint4 v2 = *(const uint4*)(po + (size_t)r2 * HDIM + i * 8);
  uint4 v3 = *(const uint4*)(po + (size_t)r3 * HDIM + i * 8);
  float o[8];
#pragma unroll
  for (int w = 0; w < 4; ++w) {
    const uint32_t a = (&v0.x)[w], b = (&v1.x)[w], c = (&v2.x)[w], d = (&v3.x)[w];
    o[w * 2 + 0] = w0 * __builtin_bit_cast(float, a << 16) +
                   w1 * __builtin_bit_cast(float, b << 16) +
                   w2v * __builtin_bit_cast(float, c << 16) +
                   w3 * __builtin_bit_cast(float, d << 16);
    o[w * 2 + 1] = w0 * __builtin_bit_cast(float, a & 0xffff0000u) +
                   w1 * __builtin_bit_cast(float, b & 0xffff0000u) +
                   w2v * __builtin_bit_cast(float, c & 0xffff0000u) +
                   w3 * __builtin_bit_cast(float, d & 0xffff0000u);
  }
  float4* o4 = (float4*)(out + (size_t)t * HDIM + i * 8);
  o4[0] = (float4){o[0], o[1], o[2], o[3]};
  o4[1] = (float4){o[4], o[5], o[6], o[7]};
}

extern "C" void kernel_launch(void* const* d_in, const int* in_sizes, int n_in,
                              void* d_out, int out_size, void* d_ws, size_t ws_size,
                              hipStream_t stream) {
  const float* x   = (const float*)d_in[0];
  const float* gw  = (const float*)d_in[1];
  const float* w1g = (const float*)d_in[2];
  const float* w1u = (const float*)d_in[3];
  const float* w2  = (const float*)d_in[4];
  float* out = (float*)d_out;

  char* ws = (char*)d_ws;
  // layout (bytes):
  //   xb     [TTOK*HDIM] bf16       @ 0           (8 MiB)
  //   hbuf   [8192,1024] bf16       @ 8388608     (16 MiB)
  //   po     [8192,2048] bf16       @ 25165824    (32 MiB)
  //   tkid   [TTOK*4] int           @ 58720256
  //   tkw    [TTOK*4] f32           @ 58753024
  //   rowTok [TTOK*4] int           @ 58785792
  //   inv    [TTOK*4] int           @ 58818560
  //   ctrl + work lists             @ 58851328
  ushort* xb     = (ushort*)(ws + 0);
  ushort* hbuf   = (ushort*)(ws + 8388608);
  ushort* po     = (ushort*)(ws + 25165824);
  int*    tkid   = (int*)   (ws + 58720256);
  float*  tkw    = (float*) (ws + 58753024);
  int*    rowTok = (int*)   (ws + 58785792);
  int*    inv    = (int*)   (ws + 58818560);
  int*    ctrl   = (int*)   (ws + 58851328);
  int* counts  = ctrl;          // 16
  int* cursors = ctrl + 16;     // 16
  int* offsets = ctrl + 32;     // 17
  int* nW1     = ctrl + 50;     // 1
  int* nW2     = ctrl + 51;     // 1
  int* wl1     = ctrl + 64;     // MAXB1 (1280)
  int* wl2     = ctrl + 64 + MAXB1;  // MAXB2 (2560)

  (void)hipMemsetAsync(ctrl, 0, 256, stream);
  router_kernel<<<TTOK / 4, 256, 0, stream>>>(x, gw, xb, tkid, tkw, counts);
  plan_kernel<<<1, 64, 0, stream>>>(counts, offsets, nW1, nW2, wl1, wl2);
  scatter_kernel<<<TTOK / 256, 256, 0, stream>>>(tkid, offsets, cursors, rowTok, inv);
  gemm1_kernel<<<MAXB1, 256, 0, stream>>>(xb, w1g, w1u, rowTok, counts, offsets,
                                          nW1, wl1, hbuf);
  gemm2_kernel<<<MAXB2, 256, 0, stream>>>(hbuf, w2, counts, offsets,
                                          nW2, wl2, po);
  combine_kernel<<<TTOK, 256, 0, stream>>>(po, inv, tkw, out);
}